// Round 2
// 378.387 us; speedup vs baseline: 1.0033x; 1.0033x over previous
//
#include <hip/hip_runtime.h>

// SVD predict + feature-concat kernel.
// 16 lanes per batch row; each lane loads one float4 of the 64-float p-row
// and q-row (16 B/lane coalescing sweet spot), streams them to the feature
// output with non-temporal stores (write-once data; keeps L2 for the random
// gathers), and contributes a 4-element partial dot reduced via __shfl_down
// over the 16-lane segment.

// clang-native 4-float vector: __builtin_nontemporal_store requires a native
// vector type, not HIP's float4 class.
typedef float vfloat4 __attribute__((ext_vector_type(4)));

__global__ __launch_bounds__(256) void svd_predict_kernel(
    const int* __restrict__ user_item,
    const float* __restrict__ pu,
    const float* __restrict__ qi,
    const float* __restrict__ bu,
    const float* __restrict__ bi,
    const float* __restrict__ gm_ptr,
    float* __restrict__ out,
    int batch)
{
    const float gm = gm_ptr[0];
    const int lane16 = threadIdx.x & 15;
    const int row = (int)((blockIdx.x * blockDim.x + threadIdx.x) >> 4);
    if (row >= batch) return;

    // single dwordx2 load of both indices (uniform across the 16-lane group,
    // served broadcast from L1)
    const int2 ui = *reinterpret_cast<const int2*>(user_item + 2 * (size_t)row);
    const int uid = ui.x;
    const int iid = ui.y;

    const vfloat4* prow = (const vfloat4*)(pu + (size_t)uid * 64);
    const vfloat4* qrow = (const vfloat4*)(qi + (size_t)iid * 64);
    vfloat4 pv = prow[lane16];
    vfloat4 qv = qrow[lane16];

    // features: out[batch + row*128 + {0..63 | 64..127}] — write-once stream,
    // bypass L2 retention with non-temporal stores (full-line writes: each
    // 16-lane group covers 256 B contiguously, no RMW risk).
    vfloat4* frow = (vfloat4*)(out + (size_t)batch + (size_t)row * 128);
    __builtin_nontemporal_store(pv, frow + lane16);
    __builtin_nontemporal_store(qv, frow + 16 + lane16);

    float s = pv.x * qv.x + pv.y * qv.y + pv.z * qv.z + pv.w * qv.w;
    // reduce across the 16-lane segment
    s += __shfl_down(s, 8, 16);
    s += __shfl_down(s, 4, 16);
    s += __shfl_down(s, 2, 16);
    s += __shfl_down(s, 1, 16);

    if (lane16 == 0) {
        float pred = gm + bu[uid] + bi[iid] + s;
        pred = fminf(fmaxf(pred, 1.0f), 5.0f);
        out[row] = pred;  // cached store: partial-line (4 B/row), keep in L2
    }
}

extern "C" void kernel_launch(void* const* d_in, const int* in_sizes, int n_in,
                              void* d_out, int out_size, void* d_ws, size_t ws_size,
                              hipStream_t stream) {
    const int*   user_item = (const int*)d_in[0];
    const float* pu        = (const float*)d_in[1];
    const float* qi        = (const float*)d_in[2];
    const float* bu        = (const float*)d_in[3];
    const float* bi        = (const float*)d_in[4];
    const float* gm        = (const float*)d_in[5];
    float*       out       = (float*)d_out;

    const int batch = in_sizes[0] / 2;           // user_item is (BATCH, 2)
    const int rows_per_block = 256 / 16;         // 16 lanes per row
    const int blocks = (batch + rows_per_block - 1) / rows_per_block;

    svd_predict_kernel<<<blocks, 256, 0, stream>>>(
        user_item, pu, qi, bu, bi, gm, out, batch);
}